// Round 2
// baseline (268.699 us; speedup 1.0000x reference)
//
#include <hip/hip_runtime.h>
#include <math.h>

#define B_ 8
#define T_ 4096
#define M_ 1024
#define TT 16          // rows per block tile; grid = B_ * (T_/TT) = 2048 blocks -> 8 blocks/CU
#define EPSF 1e-6f

// Native clang vector type: __builtin_nontemporal_store rejects HIP's
// float4 class (HIP_vector_type), but accepts ext_vector_type.
typedef float fvec4 __attribute__((ext_vector_type(4)));

// 16-tap causal bump convolution along T + per-channel softplus gate.
// out[b,t,m] = gate[m] * (1/S_t) * sum_{d=0}^{15} w[d] * x[b,t-d,m]
// w[d] = exp(1 - 1/(1 - u^2 + eps)), u = min(d/15, 1-eps); w[15] underflows to 0.
// S_t = sum_{d=0}^{min(t,15)} w[d]  (partial renorm only affects t<15).
//
// TT=16 (was 64): grid 512 -> 2048 blocks. The TT=64 version was latency-bound
// (Occupancy 18.5%, VALUBusy 13%, HBM 32% of peak) because 512 blocks = 2
// blocks/CU = 2 waves/SIMD could not hide load latency. 2048 blocks = 8
// blocks/CU = 8 waves/SIMD (VGPR=64 permits it). Halo reads grow 1.23x->1.94x
// logical but stay in L2/L3 (x is Infinity-Cache resident).
__global__ __launch_bounds__(256) void bump_conv_kernel(
    const float* __restrict__ x,
    const float* __restrict__ gate_raw,
    float* __restrict__ out) {
  const int tiles = T_ / TT;               // 256
  // XCD-aware bijective swizzle (nwg = 2048, 2048 % 8 == 0): hardware
  // round-robins blockIdx across the 8 XCDs; remap so each XCD owns a
  // contiguous run of tiles -> adjacent tiles share their 15-row halo in
  // that XCD's L2 instead of refetching from L3.
  const int nwg = B_ * tiles;              // 2048
  const int cpx = nwg / 8;                 // 256
  const int lin = (blockIdx.x % 8) * cpx + blockIdx.x / 8;
  const int tile = lin % tiles;
  const int b    = lin / tiles;
  const int t0   = tile * TT;              // multiple of 16 -> ring slot = s
  const int m    = threadIdx.x * 4;        // 256 threads * float4 = M_

  // --- taps (compile-time foldable; 16 expf worst case, negligible) ---
  float w[16];
  float S = 0.0f;
#pragma unroll
  for (int d = 0; d < 16; ++d) {
    float u = fminf((float)d * (1.0f / 15.0f), 1.0f - EPSF);
    float den = 1.0f - u * u + EPSF;
    w[d] = expf(1.0f - 1.0f / den);        // d=15 -> expf(-3.3e5) == 0.0f
    S += w[d];
  }
  const float rsS = 1.0f / fmaxf(S, EPSF);

  // --- per-channel gate: softplus(gate_raw) ---
  const fvec4 graw = *(const fvec4*)(gate_raw + m);
  fvec4 g;
  g.x = fmaxf(graw.x, 0.0f) + log1pf(expf(-fabsf(graw.x)));
  g.y = fmaxf(graw.y, 0.0f) + log1pf(expf(-fabsf(graw.y)));
  g.z = fmaxf(graw.z, 0.0f) + log1pf(expf(-fabsf(graw.z)));
  g.w = fmaxf(graw.w, 0.0f) + log1pf(expf(-fabsf(graw.w)));

  const float* xb = x   + (size_t)b * T_ * M_ + m;
  float*       ob = out + (size_t)b * T_ * M_ + m;

  // --- ring buffer: slot for row t is (t & 15) ---
  fvec4 r[16];
  r[0] = (fvec4)(0.f);
#pragma unroll
  for (int k = 1; k <= 15; ++k) {          // halo rows t0-15 .. t0-1 -> slots 1..15
    const int t = t0 - 16 + k;
    r[k] = (t >= 0) ? *(const fvec4*)(xb + (size_t)t * M_)
                    : (fvec4)(0.f);
  }
  fvec4 nxt = *(const fvec4*)(xb + (size_t)t0 * M_);  // prefetch row t0

#pragma unroll
  for (int s = 0; s < 16; ++s) {
    const int t = t0 + s;
    const fvec4 cur = nxt;
    if (s < 15)                            // last row of tile: nothing to prefetch
      nxt = *(const fvec4*)(xb + (size_t)(t + 1) * M_);
    r[s] = cur;                            // (t & 15) == s since t0 % 16 == 0

    float ax = 0.f, ay = 0.f, az = 0.f, aw = 0.f;
#pragma unroll
    for (int d = 0; d < 16; ++d) {
      const fvec4 v = r[(s - d + 16) & 15];  // compile-time index
      const float wd = w[d];
      ax = fmaf(wd, v.x, ax);
      ay = fmaf(wd, v.y, ay);
      az = fmaf(wd, v.z, az);
      aw = fmaf(wd, v.w, aw);
    }

    float sc = rsS;
    if (t < 15) {                          // wave-uniform; only tile 0
      float p = 0.0f;
#pragma unroll
      for (int d = 0; d < 16; ++d) p += (d <= t) ? w[d] : 0.0f;
      sc = 1.0f / fmaxf(p, EPSF);
    }

    fvec4 o;
    o.x = ax * sc * g.x;
    o.y = ay * sc * g.y;
    o.z = az * sc * g.z;
    o.w = aw * sc * g.w;
    // Output is write-once/never-read: nontemporal store keeps it from
    // evicting x (134 MB) out of the 256 MB Infinity Cache.
    __builtin_nontemporal_store(o, (fvec4*)(ob + (size_t)t * M_));
  }
}

extern "C" void kernel_launch(void* const* d_in, const int* in_sizes, int n_in,
                              void* d_out, int out_size, void* d_ws, size_t ws_size,
                              hipStream_t stream) {
  const float* x         = (const float*)d_in[0];
  // d_in[1] = mask (T,T): redundant (taps already causal) -- intentionally unread.
  const float* gate_raw  = (const float*)d_in[2];
  float*       out       = (float*)d_out;

  dim3 grid(B_ * (T_ / TT));   // 2048 blocks
  dim3 block(256);
  bump_conv_kernel<<<grid, block, 0, stream>>>(x, gate_raw, out);
}

// Round 3
// 263.135 us; speedup vs baseline: 1.0211x; 1.0211x over previous
//
#include <hip/hip_runtime.h>
#include <math.h>

#define B_ 8
#define T_ 4096
#define M_ 1024
#define TT 32          // rows per block tile; grid = B_ * (T_/TT) = 1024 blocks
#define CH 8           // chunk rows: 8 independent loads in flight per wave (MLP=8)
#define EPSF 1e-6f

// Native clang vector type: __builtin_nontemporal_store rejects HIP's
// float4 class (HIP_vector_type), but accepts ext_vector_type.
typedef float fvec4 __attribute__((ext_vector_type(4)));

// 16-tap causal bump convolution along T + per-channel softplus gate.
// out[b,t,m] = gate[m] * (1/S_t) * sum_{d=0}^{15} w[d] * x[b,t-d,m]
//
// Round-2 post-mortem: occupancy 18.5->40.9% did NOT move hbm_gbps (pinned at
// ~2.4-2.6 TB/s in both configs). The limit is per-wave MLP: prefetch depth 1
// means one dependent load chain per wave; waves multiply chains, not
// outstanding bytes. Fix: chunked register double-buffer — while computing 8
// rows (~1100 issue-cycles), the NEXT 8 row loads (8 KB/wave) are in flight.
// At even 2 waves/SIMD that is 64 KB in flight per CU vs the ~9 KB needed to
// saturate HBM (10 B/cy x ~900 cy). Full unroll keeps every array index
// compile-time (runtime-indexed ext_vector arrays spill to scratch).
__global__ __launch_bounds__(256) void bump_conv_kernel(
    const float* __restrict__ x,
    const float* __restrict__ gate_raw,
    float* __restrict__ out) {
  const int tiles = T_ / TT;               // 128
  // XCD-aware bijective swizzle (nwg = 1024, 1024 % 8 == 0): each XCD owns a
  // contiguous run of tiles so co-resident neighbors share their 15-row halo
  // in that XCD's L2.
  const int nwg = B_ * tiles;              // 1024
  const int cpx = nwg / 8;                 // 128
  const int lin = (blockIdx.x % 8) * cpx + blockIdx.x / 8;
  const int tile = lin % tiles;
  const int b    = lin / tiles;
  const int t0   = tile * TT;              // multiple of 16 -> ring slot = t & 15
  const int m    = threadIdx.x * 4;        // 256 threads * float4 = M_

  // --- taps ---
  float w[16];
  float S = 0.0f;
#pragma unroll
  for (int d = 0; d < 16; ++d) {
    float u = fminf((float)d * (1.0f / 15.0f), 1.0f - EPSF);
    float den = 1.0f - u * u + EPSF;
    w[d] = expf(1.0f - 1.0f / den);        // d=15 -> expf(-3.3e5) == 0.0f
    S += w[d];
  }
  const float rsS = 1.0f / fmaxf(S, EPSF);

  // --- per-channel gate: softplus(gate_raw) ---
  const fvec4 graw = *(const fvec4*)(gate_raw + m);
  fvec4 g;
  g.x = fmaxf(graw.x, 0.0f) + log1pf(expf(-fabsf(graw.x)));
  g.y = fmaxf(graw.y, 0.0f) + log1pf(expf(-fabsf(graw.y)));
  g.z = fmaxf(graw.z, 0.0f) + log1pf(expf(-fabsf(graw.z)));
  g.w = fmaxf(graw.w, 0.0f) + log1pf(expf(-fabsf(graw.w)));

  const float* xb = x   + (size_t)b * T_ * M_ + m;
  float*       ob = out + (size_t)b * T_ * M_ + m;

  // --- ring buffer: slot for row t is (t & 15) ---
  fvec4 r[16];
  r[0] = (fvec4)(0.f);
#pragma unroll
  for (int k = 1; k <= 15; ++k) {          // halo rows t0-15 .. t0-1 -> slots 1..15
    const int t = t0 - 16 + k;
    r[k] = (t >= 0) ? *(const fvec4*)(xb + (size_t)t * M_)
                    : (fvec4)(0.f);
  }

  // --- chunk double-buffer in registers; all indices static after unroll ---
  fvec4 pb[2][CH];
#pragma unroll
  for (int s = 0; s < CH; ++s)             // chunk 0: 8 independent loads
    pb[0][s] = *(const fvec4*)(xb + (size_t)(t0 + s) * M_);

#pragma unroll
  for (int c = 0; c < TT / CH; ++c) {      // 4 chunks, fully unrolled
    const int cur = c & 1;
    const int nxb = cur ^ 1;
    const int tc  = t0 + c * CH;

    if (c + 1 < TT / CH) {                 // issue next chunk's 8 loads (in
#pragma unroll                             // flight during this chunk's FMAs)
      for (int s = 0; s < CH; ++s)
        pb[nxb][s] = *(const fvec4*)(xb + (size_t)(tc + CH + s) * M_);
    }

#pragma unroll
    for (int s = 0; s < CH; ++s) {
      const int t = tc + s;
      r[(c * CH + s) & 15] = pb[cur][s];   // slot (t & 15); static index

      float ax = 0.f, ay = 0.f, az = 0.f, aw = 0.f;
#pragma unroll
      for (int d = 0; d < 16; ++d) {
        const fvec4 v = r[((c * CH + s) - d + 16) & 15];  // static index
        const float wd = w[d];
        ax = fmaf(wd, v.x, ax);
        ay = fmaf(wd, v.y, ay);
        az = fmaf(wd, v.z, az);
        aw = fmaf(wd, v.w, aw);
      }

      float sc = rsS;
      if (t < 15) {                        // wave-uniform; only tile 0
        float p = 0.0f;
#pragma unroll
        for (int d = 0; d < 16; ++d) p += (d <= t) ? w[d] : 0.0f;
        sc = 1.0f / fmaxf(p, EPSF);
      }

      fvec4 o;
      o.x = ax * sc * g.x;
      o.y = ay * sc * g.y;
      o.z = az * sc * g.z;
      o.w = aw * sc * g.w;
      // Output is write-once/never-read: nontemporal store keeps it from
      // evicting x out of the Infinity Cache.
      __builtin_nontemporal_store(o, (fvec4*)(ob + (size_t)t * M_));
    }
  }
}

extern "C" void kernel_launch(void* const* d_in, const int* in_sizes, int n_in,
                              void* d_out, int out_size, void* d_ws, size_t ws_size,
                              hipStream_t stream) {
  const float* x         = (const float*)d_in[0];
  // d_in[1] = mask (T,T): redundant (taps already causal) -- intentionally unread.
  const float* gate_raw  = (const float*)d_in[2];
  float*       out       = (float*)d_out;

  dim3 grid(B_ * (T_ / TT));   // 1024 blocks
  dim3 block(256);
  bump_conv_kernel<<<grid, block, 0, stream>>>(x, gate_raw, out);
}